// Round 4
// baseline (291.168 us; speedup 1.0000x reference)
//
#include <hip/hip_runtime.h>

// Problem constants (from reference setup_inputs)
constexpr int NA = 256;   // N_AGENTS
constexpr int B  = 64;    // BATCH
constexpr int S  = 20;    // SEQ
constexpr int H  = 128;   // HID

constexpr int AGENTS_PER_BLOCK = 16;  // 4 waves x 4 agents each
constexpr int BLOCKS = (NA / AGENTS_PER_BLOCK) * B;  // 16 * 64 = 1024

// R4 = R3 kernel, UNCHANGED, launched 4x back-to-back as a timing diagnostic:
// dur_us = harness_overhead + 4*t_kernel, so t_kernel = (dur_R4 - dur_R3)/3.
// The kernel is pure/deterministic -> relaunch writes bit-identical output;
// graph capture sees 4 identical dispatches (same work every call).
__global__ __launch_bounds__(256, 4) void social_pool_kernel(
    const float* __restrict__ h,    // (NA, B, S, H)
    const float* __restrict__ p,    // (NA, B, S, 2)
    const float* __restrict__ rptr, // scalar radius
    float* __restrict__ out)        // (NA, B, H)
{
    const int group = blockIdx.x & (NA / AGENTS_PER_BLOCK - 1);  // 0..15
    const int b     = blockIdx.x >> 4;                           // 0..63
    const int tid   = threadIdx.x;
    const int wave  = tid >> 6;   // 0..3
    const int lane  = tid & 63;

    __shared__ float px[NA];
    __shared__ float py[NA];

    // Stage this batch's 256 last-timestep positions (scattered 8B loads).
    {
        const int j = tid;  // 256 threads, 256 agents
        const float2 pj = *(const float2*)(p + (((size_t)(j * B + b)) * S + (S - 1)) * 2);
        px[j] = pj.x;
        py[j] = pj.y;
    }
    __syncthreads();

    const float r = *rptr;
    const int ibase = group * AGENTS_PER_BLOCK + wave * 4;

    // Build neighbor bitmasks for all 4 agents: 16 wave-uniform 64-bit words.
    unsigned long long m[4][4];
    int n[4];
    #pragma unroll
    for (int a = 0; a < 4; ++a) {
        const int i = ibase + a;
        const float xi = px[i];
        const float yi = py[i];
        #pragma unroll
        for (int k = 0; k < 4; ++k) {
            const int j = (k << 6) + lane;
            const float dx   = __fsub_rn(xi, px[j]);
            const float dy   = __fsub_rn(yi, py[j]);
            const float d2   = __fadd_rn(__fmul_rn(dx, dx), __fmul_rn(dy, dy));
            const float dist = __fsqrt_rn(d2);
            m[a][k] = __ballot(dist <= r);
        }
        m[a][i >> 6] &= ~(1ull << (i & 63));  // exclude self
        n[a] = __popcll(m[a][0]) + __popcll(m[a][1]) + __popcll(m[a][2]) + __popcll(m[a][3]);
    }

    const size_t jstride = (size_t)B * S * H;
    const float* hb = h + ((size_t)b * S + (S - 1)) * H + 2 * lane;

    // Fused gather: one bit from each of the 16 words per round -> up to 16
    // independent loads in flight before the accumulate's waitcnt.
    float ax[4] = {0.f, 0.f, 0.f, 0.f};
    float ay[4] = {0.f, 0.f, 0.f, 0.f};
    bool any = (m[0][0] | m[0][1] | m[0][2] | m[0][3] |
                m[1][0] | m[1][1] | m[1][2] | m[1][3] |
                m[2][0] | m[2][1] | m[2][2] | m[2][3] |
                m[3][0] | m[3][1] | m[3][2] | m[3][3]) != 0ull;
    while (any) {
        float2 v[16];
        bool   got[16];
        #pragma unroll
        for (int w = 0; w < 16; ++w) {
            const int a = w >> 2, k = w & 3;
            got[w] = (m[a][k] != 0ull);
            if (got[w]) {
                const int j = (k << 6) + __builtin_ctzll(m[a][k]);
                m[a][k] &= m[a][k] - 1ull;
                v[w] = *(const float2*)(hb + (size_t)j * jstride);
            }
        }
        #pragma unroll
        for (int w = 0; w < 16; ++w) {
            const int a = w >> 2;
            if (got[w]) { ax[a] += v[w].x; ay[a] += v[w].y; }
        }
        any = (m[0][0] | m[0][1] | m[0][2] | m[0][3] |
               m[1][0] | m[1][1] | m[1][2] | m[1][3] |
               m[2][0] | m[2][1] | m[2][2] | m[2][3] |
               m[3][0] | m[3][1] | m[3][2] | m[3][3]) != 0ull;
    }

    #pragma unroll
    for (int a = 0; a < 4; ++a) {
        const int i = ibase + a;
        const float c = (float)(n[a] > 0 ? n[a] : 1);
        float2 o;
        o.x = __fdiv_rn(ax[a], c);
        o.y = __fdiv_rn(ay[a], c);
        *(float2*)(out + ((size_t)i * B + b) * H + 2 * lane) = o;
    }
}

extern "C" void kernel_launch(void* const* d_in, const int* in_sizes, int n_in,
                              void* d_out, int out_size, void* d_ws, size_t ws_size,
                              hipStream_t stream) {
    const float* h    = (const float*)d_in[0];
    const float* p    = (const float*)d_in[1];
    const float* rptr = (const float*)d_in[2];
    float* out        = (float*)d_out;

    (void)in_sizes; (void)n_in; (void)out_size; (void)d_ws; (void)ws_size;

    // Diagnostic: 4 identical launches -> t_kernel = (dur - dur_single)/3.
    for (int rep = 0; rep < 4; ++rep) {
        social_pool_kernel<<<dim3(BLOCKS), dim3(256), 0, stream>>>(h, p, rptr, out);
    }
}

// Round 5
// 288.601 us; speedup vs baseline: 1.0089x; 1.0089x over previous
//
#include <hip/hip_runtime.h>

// Problem constants (from reference setup_inputs)
constexpr int NA = 256;   // N_AGENTS
constexpr int B  = 64;    // BATCH
constexpr int S  = 20;    // SEQ
constexpr int H  = 128;   // HID

constexpr int AGENTS_PER_BLOCK = 16;  // 4 waves x 4 agents each
constexpr int BLOCKS = (NA / AGENTS_PER_BLOCK) * B;  // 16 * 64 = 1024

// R5 change vs R4: XCD-aware blockIdx swizzle. Consecutive blockIdx round-robin
// across the 8 XCDs, so the R4 decode (b = blockIdx>>4) spread each batch's 16
// blocks over all 8 XCDs -> every XCD touched all 64 batches (8.4 MB h-rows >
// 4 MB per-XCD L2) -> thrash -> gather ran at L3 BW (~5.1 TB/s observed).
// New decode pins batch b entirely to XCD b%8: per-XCD working set 8 batches
// x 131 KB = 1 MB, fits L2. Perf-only heuristic; correctness is
// dispatch-order-independent. Per-wave work/order unchanged -> bit-identical.
// Still 4x diagnostic launches: t_kernel = (dur - 193us_overhead)/4.
__global__ __launch_bounds__(256, 4) void social_pool_kernel(
    const float* __restrict__ h,    // (NA, B, S, H)
    const float* __restrict__ p,    // (NA, B, S, 2)
    const float* __restrict__ rptr, // scalar radius
    float* __restrict__ out)        // (NA, B, H)
{
    const int xcd   = blockIdx.x & 7;         // round-robin XCD assignment
    const int slot  = blockIdx.x >> 3;        // 0..127
    const int b     = ((slot & 7) << 3) + xcd; // batch: pinned to XCD b%8
    const int group = slot >> 3;              // 0..15
    const int tid   = threadIdx.x;
    const int wave  = tid >> 6;   // 0..3
    const int lane  = tid & 63;

    __shared__ float px[NA];
    __shared__ float py[NA];

    // Stage this batch's 256 last-timestep positions (scattered 8B loads).
    {
        const int j = tid;  // 256 threads, 256 agents
        const float2 pj = *(const float2*)(p + (((size_t)(j * B + b)) * S + (S - 1)) * 2);
        px[j] = pj.x;
        py[j] = pj.y;
    }
    __syncthreads();

    const float r = *rptr;
    const int ibase = group * AGENTS_PER_BLOCK + wave * 4;

    // Build neighbor bitmasks for all 4 agents: 16 wave-uniform 64-bit words.
    unsigned long long m[4][4];
    int n[4];
    #pragma unroll
    for (int a = 0; a < 4; ++a) {
        const int i = ibase + a;
        const float xi = px[i];
        const float yi = py[i];
        #pragma unroll
        for (int k = 0; k < 4; ++k) {
            const int j = (k << 6) + lane;
            const float dx   = __fsub_rn(xi, px[j]);
            const float dy   = __fsub_rn(yi, py[j]);
            const float d2   = __fadd_rn(__fmul_rn(dx, dx), __fmul_rn(dy, dy));
            const float dist = __fsqrt_rn(d2);
            m[a][k] = __ballot(dist <= r);
        }
        m[a][i >> 6] &= ~(1ull << (i & 63));  // exclude self
        n[a] = __popcll(m[a][0]) + __popcll(m[a][1]) + __popcll(m[a][2]) + __popcll(m[a][3]);
    }

    const size_t jstride = (size_t)B * S * H;
    const float* hb = h + ((size_t)b * S + (S - 1)) * H + 2 * lane;

    // Fused gather: one bit from each of the 16 words per round -> up to 16
    // independent coalesced 512B row loads in flight per round.
    float ax[4] = {0.f, 0.f, 0.f, 0.f};
    float ay[4] = {0.f, 0.f, 0.f, 0.f};
    bool any = (m[0][0] | m[0][1] | m[0][2] | m[0][3] |
                m[1][0] | m[1][1] | m[1][2] | m[1][3] |
                m[2][0] | m[2][1] | m[2][2] | m[2][3] |
                m[3][0] | m[3][1] | m[3][2] | m[3][3]) != 0ull;
    while (any) {
        float2 v[16];
        bool   got[16];
        #pragma unroll
        for (int w = 0; w < 16; ++w) {
            const int a = w >> 2, k = w & 3;
            got[w] = (m[a][k] != 0ull);
            if (got[w]) {
                const int j = (k << 6) + __builtin_ctzll(m[a][k]);
                m[a][k] &= m[a][k] - 1ull;
                v[w] = *(const float2*)(hb + (size_t)j * jstride);
            }
        }
        #pragma unroll
        for (int w = 0; w < 16; ++w) {
            const int a = w >> 2;
            if (got[w]) { ax[a] += v[w].x; ay[a] += v[w].y; }
        }
        any = (m[0][0] | m[0][1] | m[0][2] | m[0][3] |
               m[1][0] | m[1][1] | m[1][2] | m[1][3] |
               m[2][0] | m[2][1] | m[2][2] | m[2][3] |
               m[3][0] | m[3][1] | m[3][2] | m[3][3]) != 0ull;
    }

    #pragma unroll
    for (int a = 0; a < 4; ++a) {
        const int i = ibase + a;
        const float c = (float)(n[a] > 0 ? n[a] : 1);
        float2 o;
        o.x = __fdiv_rn(ax[a], c);
        o.y = __fdiv_rn(ay[a], c);
        *(float2*)(out + ((size_t)i * B + b) * H + 2 * lane) = o;
    }
}

extern "C" void kernel_launch(void* const* d_in, const int* in_sizes, int n_in,
                              void* d_out, int out_size, void* d_ws, size_t ws_size,
                              hipStream_t stream) {
    const float* h    = (const float*)d_in[0];
    const float* p    = (const float*)d_in[1];
    const float* rptr = (const float*)d_in[2];
    float* out        = (float*)d_out;

    (void)in_sizes; (void)n_in; (void)out_size; (void)d_ws; (void)ws_size;

    // Diagnostic: 4 identical launches -> isolates t_kernel from ~193us harness
    // fixed overhead (fills + input restore).
    for (int rep = 0; rep < 4; ++rep) {
        social_pool_kernel<<<dim3(BLOCKS), dim3(256), 0, stream>>>(h, p, rptr, out);
    }
}

// Round 6
// 282.059 us; speedup vs baseline: 1.0323x; 1.0232x over previous
//
#include <hip/hip_runtime.h>

// Problem constants (from reference setup_inputs)
constexpr int NA = 256;   // N_AGENTS
constexpr int B  = 64;    // BATCH
constexpr int S  = 20;    // SEQ
constexpr int H  = 128;   // HID

constexpr int BLOCKS  = 256;   // 4 blocks per batch (agent quarters); 1 block/CU
constexpr int THREADS = 1024;  // 16 waves

// R6: full LDS row-staging. R2-R5 evidence: gather flight depth (R2~R3) and
// XCD locality (R4~R5) both neutral at t_kernel ~24us -> the ~245k scattered
// global 512B row-loads (~2M line transactions) through the vector-memory path
// are the suspect. This version stages ALL 256 h_last rows of the batch into
// LDS (128 KB) with coalesced wave-loads, then gathers neighbors from LDS
// (ds_read_b64, minimal 4-cycle wave access, zero bank conflicts).
// Global traffic: 33.6 MB staged (8.4 compulsory) + 8.4 MB out. Global
// row-gather count: 0.
// Numerics: distance bit-exact vs numpy fp32 -> __f*_rn, no FMA contraction,
// correctly-rounded sqrt, inclusive <=; __fdiv_rn epilogue. Bit-level only
// sum order changes (ulp).
__global__ __launch_bounds__(1024, 1) void social_pool_kernel(
    const float* __restrict__ h,    // (NA, B, S, H)
    const float* __restrict__ p,    // (NA, B, S, 2)
    const float* __restrict__ rptr, // scalar radius
    float* __restrict__ out)        // (NA, B, H)
{
    const int q    = blockIdx.x & 3;   // agent quarter: i in [q*64, q*64+64)
    const int b    = blockIdx.x >> 2;  // batch
    const int tid  = threadIdx.x;
    const int wave = tid >> 6;         // 0..15
    const int lane = tid & 63;

    __shared__ float hrow[NA * H];     // 128 KB: all 256 rows of this batch
    __shared__ float px[NA];
    __shared__ float py[NA];

    // Positions (scattered 8B loads, 4 of the 16 waves).
    if (tid < NA) {
        const float2 pj = *(const float2*)(p + (((size_t)(tid * B + b)) * S + (S - 1)) * 2);
        px[tid] = pj.x;
        py[tid] = pj.y;
    }

    // Stage all 256 h_last rows: wave w stages rows {it*16 + w}.
    // One row = one coalesced 512B wave-load (dwordx2/lane); 16 independent
    // loads per wave pipeline freely.
    const size_t jstride = (size_t)B * S * H;
    const size_t hlast   = ((size_t)b * S + (S - 1)) * H;
    #pragma unroll
    for (int it = 0; it < 16; ++it) {
        const int row = it * 16 + wave;
        const float2 v = *(const float2*)(h + (size_t)row * jstride + hlast + 2 * lane);
        *(float2*)(&hrow[row * H + 2 * lane]) = v;
    }
    __syncthreads();

    const float radius = *rptr;
    const int ibase = q * 64 + wave * 4;

    // Each wave handles 4 agents; masks are wave-uniform (SGPR) after ballot.
    #pragma unroll
    for (int a = 0; a < 4; ++a) {
        const int i = ibase + a;
        const float xi = px[i];
        const float yi = py[i];

        unsigned long long m[4];
        #pragma unroll
        for (int k = 0; k < 4; ++k) {
            const int j = (k << 6) + lane;
            const float dx   = __fsub_rn(xi, px[j]);
            const float dy   = __fsub_rn(yi, py[j]);
            const float d2   = __fadd_rn(__fmul_rn(dx, dx), __fmul_rn(dy, dy));
            const float dist = __fsqrt_rn(d2);
            m[k] = __ballot(dist <= radius);
        }
        m[i >> 6] &= ~(1ull << (i & 63));  // exclude self
        const int n = __popcll(m[0]) + __popcll(m[1]) + __popcll(m[2]) + __popcll(m[3]);

        // Gather neighbor rows from LDS, 4 words interleaved.
        float ax = 0.0f, ay = 0.0f;
        while (m[0] | m[1] | m[2] | m[3]) {
            float2 v[4];
            bool got[4];
            #pragma unroll
            for (int k = 0; k < 4; ++k) {
                got[k] = (m[k] != 0ull);
                if (got[k]) {
                    const int j = (k << 6) + __builtin_ctzll(m[k]);
                    m[k] &= m[k] - 1ull;
                    v[k] = *(const float2*)(&hrow[j * H + 2 * lane]);
                }
            }
            #pragma unroll
            for (int k = 0; k < 4; ++k) {
                if (got[k]) { ax += v[k].x; ay += v[k].y; }
            }
        }

        const float c = (float)(n > 0 ? n : 1);
        float2 o;
        o.x = __fdiv_rn(ax, c);
        o.y = __fdiv_rn(ay, c);
        *(float2*)(out + ((size_t)i * B + b) * H + 2 * lane) = o;
    }
}

extern "C" void kernel_launch(void* const* d_in, const int* in_sizes, int n_in,
                              void* d_out, int out_size, void* d_ws, size_t ws_size,
                              hipStream_t stream) {
    const float* h    = (const float*)d_in[0];
    const float* p    = (const float*)d_in[1];
    const float* rptr = (const float*)d_in[2];
    float* out        = (float*)d_out;

    (void)in_sizes; (void)n_in; (void)out_size; (void)d_ws; (void)ws_size;

    // Diagnostic: 4 identical launches -> t_kernel = (dur - 193us overhead)/4.
    for (int rep = 0; rep < 4; ++rep) {
        social_pool_kernel<<<dim3(BLOCKS), dim3(THREADS), 0, stream>>>(h, p, rptr, out);
    }
}